// Round 3
// baseline (1095.889 us; speedup 1.0000x reference)
//
#include <hip/hip_runtime.h>
#include <hip/hip_bf16.h>
#include <math.h>

// Problem constants
#define B_   4
#define S_   2048
#define D_   2048
#define H_   16
#define HD_  128
#define N3_  6144   // 3*D
#define M_   8192   // B*S
#define NT_  32     // S/64 q-tiles

typedef __attribute__((ext_vector_type(8))) short  short8;
typedef __attribute__((ext_vector_type(4))) float  float4_;

using bf16 = __hip_bfloat16;

static __device__ __forceinline__ float bf2f(bf16 v){ return __bfloat162float(v); }
static __device__ __forceinline__ bf16  f2bf(float v){ return __float2bfloat16(v); }
static __device__ __forceinline__ short f2bfs(float v){
    return (short)__builtin_bit_cast(unsigned short, __float2bfloat16(v));
}

// load 8 elements as bf16 short8 — overloaded on source dtype
static __device__ __forceinline__ short8 load8(const bf16* p){ return *(const short8*)p; }
static __device__ __forceinline__ short8 load8(const float* p){
    float4_ a = *(const float4_*)p;
    float4_ b = *(const float4_*)(p + 4);
    short8 r;
    r[0]=f2bfs(a[0]); r[1]=f2bfs(a[1]); r[2]=f2bfs(a[2]); r[3]=f2bfs(a[3]);
    r[4]=f2bfs(b[0]); r[5]=f2bfs(b[1]); r[6]=f2bfs(b[2]); r[7]=f2bfs(b[3]);
    return r;
}

// async global->LDS 16B copy (global_load_lds_dwordx4)
static __device__ __forceinline__ void cp16_g2l(const void* g, void* l){
    __builtin_amdgcn_global_load_lds((const __attribute__((address_space(1))) void*)g,
                                     (__attribute__((address_space(3))) void*)l,
                                     16, 0, 0);
}

// ---------------- cast fp32 -> bf16 (fast path only) ----------------
__global__ void cast_f32_bf16(const float* __restrict__ in, bf16* __restrict__ out, long n8){
    long i = (long)blockIdx.x * blockDim.x + threadIdx.x;
    if (i >= n8) return;
    *((short8*)out + i) = load8(in + 8*i);
}

// ---------------- bf16 MFMA GEMM: C = A * Bt^T + bias ----------------
// bf16 x bf16 path stages via global_load_lds width=16 (m97 ladder step).
template<typename AT, typename BT, typename OUT_T>
__global__ __launch_bounds__(256) void gemm_bt(const AT* __restrict__ A, int lda,
                                               const BT* __restrict__ Bt, int ldb,
                                               const float* __restrict__ bias,
                                               OUT_T* __restrict__ C, int ldc, int Kdim){
    constexpr bool ASYNC = (sizeof(AT) == 2) && (sizeof(BT) == 2);
    __shared__ __align__(16) bf16 As[128*32];
    __shared__ __align__(16) bf16 Bs[128*32];
    const int tid  = threadIdx.x;
    const int lane = tid & 63;
    const int w    = tid >> 6;
    const int wm   = w >> 1, wn = w & 1;
    const int quad = lane >> 4, l15 = lane & 15;
    const int bn0  = blockIdx.x * 128, bm0 = blockIdx.y * 128;
    const int srow = tid >> 2;          // 0..63
    const int scol = (tid & 3) * 8;     // 0,8,16,24

    float4_ acc[4][4] = {};

    for (int k0 = 0; k0 < Kdim; k0 += 32){
        __syncthreads();
        if constexpr (ASYNC){
            const int cb = (tid & 3) * 16;   // byte col within 64B k-slab
            const int rr = tid >> 2;
            #pragma unroll
            for (int hf = 0; hf < 2; ++hf){
                const int r = hf*64 + rr;
                cp16_g2l((const char*)(A  + (size_t)(bm0 + r)*lda + k0) + cb, (char*)As + r*64 + cb);
                cp16_g2l((const char*)(Bt + (size_t)(bn0 + r)*ldb + k0) + cb, (char*)Bs + r*64 + cb);
            }
        } else {
            #pragma unroll
            for (int half = 0; half < 2; ++half){
                int r = half*64 + srow;
                *(short8*)&As[r*32 + scol] = load8(&A[(size_t)(bm0 + r)*lda + k0 + scol]);
                *(short8*)&Bs[r*32 + scol] = load8(&Bt[(size_t)(bn0 + r)*ldb + k0 + scol]);
            }
        }
        __syncthreads();
        short8 af[4], bfr[4];
        #pragma unroll
        for (int mt = 0; mt < 4; ++mt) af[mt]  = *(const short8*)&As[(wm*64 + mt*16 + l15)*32 + quad*8];
        #pragma unroll
        for (int nt = 0; nt < 4; ++nt) bfr[nt] = *(const short8*)&Bs[(wn*64 + nt*16 + l15)*32 + quad*8];
        #pragma unroll
        for (int mt = 0; mt < 4; ++mt)
            #pragma unroll
            for (int nt = 0; nt < 4; ++nt)
                acc[mt][nt] = __builtin_amdgcn_mfma_f32_16x16x32_bf16(af[mt], bfr[nt], acc[mt][nt], 0, 0, 0);
    }

    // epilogue: C/D layout col=lane&15, row=quad*4+reg (m89/m91 verified)
    #pragma unroll
    for (int mt = 0; mt < 4; ++mt){
        int row = bm0 + wm*64 + mt*16 + quad*4;
        #pragma unroll
        for (int nt = 0; nt < 4; ++nt){
            int col = bn0 + wn*64 + nt*16 + l15;
            float bia = bias[col];
            #pragma unroll
            for (int r = 0; r < 4; ++r){
                float v = acc[mt][nt][r] + bia;
                size_t idx = (size_t)(row + r)*ldc + col;
                if constexpr (sizeof(OUT_T) == 2) ((bf16*)C)[idx] = f2bf(v);
                else                              ((float*)C)[idx] = v;
            }
        }
    }
}

// ---------------- RoPE apply in-place on q,k inside qkv (inline trig) --------
__global__ void rope_apply(bf16* __restrict__ qkv){
    int idx = blockIdx.x * blockDim.x + threadIdx.x;  // ((b*S+s)*H + h)*64 + p
    int p = idx & 63;
    int h = (idx >> 6) & (H_-1);
    int s = (idx >> 10) & (S_-1);
    int b = idx >> 21;
    float freq = powf(10000.0f, -(float)(2*p) / (float)HD_);
    float ang = (float)s * freq;
    float c = cosf(ang), sn = sinf(ang);
    size_t base = (size_t)(b*S_ + s) * N3_ + h*HD_ + 2*p;
    float tr = bf2f(qkv[base]), ti = bf2f(qkv[base+1]);
    qkv[base]   = f2bf(tr*c - ti*sn);
    qkv[base+1] = f2bf(tr*sn + ti*c);
    size_t kb = base + D_;
    tr = bf2f(qkv[kb]); ti = bf2f(qkv[kb+1]);
    qkv[kb]   = f2bf(tr*c - ti*sn);
    qkv[kb+1] = f2bf(tr*sn + ti*c);
}

// ---------------- causal flash attention ----------------
// Balanced pairing: block (tp,bh) processes q-tiles tp and 31-tp sequentially
// -> every block does exactly 33 k-chunks (uniform work, no causal tail).
// KVBLK=64 keys/chunk. K stored linear [64][128] with G4 XOR swizzle
// (byte ^= (row&7)<<4): spread b128 frag reads. V stored transposed
// [d=128][key=64] with the same XOR. P roundtrip buffer: per-wave [16][64]
// (128B rows) with the same XOR swizzle — zero pad, 4 blocks/CU (40960B LDS).
// Softmax in exp2 domain (scale folded with log2e). setprio(1) around MFMA.
__global__ __launch_bounds__(256, 4) void attn(bf16* __restrict__ QKV){
    const int tp = blockIdx.x, bh = blockIdx.y;
    const int b = bh >> 4, h = bh & 15;
    const int tid = threadIdx.x;
    const int w = tid >> 6, lane = tid & 63, quad = lane >> 4, l15 = lane & 15;
    bf16* Qp = QKV + (size_t)b*S_*N3_ + h*HD_;
    const bf16* Kp = Qp + D_;
    const bf16* Vp = Qp + 2*D_;
    __shared__ __align__(16) bf16 Ks[64*128];      // [key][d], XOR swizzled
    __shared__ __align__(16) bf16 Vt[128*64];      // [d][key], XOR swizzled
    __shared__ __align__(16) bf16 Pls[4*16*64];    // per-wave [16][64], XOR swizzled

    // staging ids: 4 lanes cover one key's 128 d (64B each), 64 keys/block
    const int skey = tid >> 2;           // 0..63
    const int scb  = (tid & 3) * 64;     // byte col base within 256B row
    const int kswz = (skey & 7) << 4;

    const float scale2 = 0.12751707470412558f;  // (1/sqrt(128)) * log2(e)

    for (int half = 0; half < 2; ++half){
        const int t = half ? (NT_ - 1 - tp) : tp;
        const int qrow = t*64 + w*16 + l15;
        short8 qf[4];
        #pragma unroll
        for (int kc = 0; kc < 4; ++kc)
            qf[kc] = *(const short8*)&Qp[(size_t)qrow*N3_ + kc*32 + quad*8];

        float4_ accO[8] = {};
        float m_i[4], l_i[4];
        #pragma unroll
        for (int r = 0; r < 4; ++r){ m_i[r] = -3.0e38f; l_i[r] = 0.0f; }
        const int rbase = t*64 + w*16 + quad*4;
        const int nch = t + 1;

        for (int c = 0; c < nch; ++c){
            const int kb = c * 64;
            __syncthreads();   // WAR: all frag reads of previous chunk done
            // ---- stage K (swizzled linear) + V (transposed, swizzled) ----
            {
                const char* krow = (const char*)&Kp[(size_t)(kb + skey)*N3_] + scb;
                const char* vrow = (const char*)&Vp[(size_t)(kb + skey)*N3_] + scb;
                #pragma unroll
                for (int u = 0; u < 4; ++u)
                    *(short8*)((char*)Ks + ((skey*256 + scb + u*16) ^ kswz)) =
                        *(const short8*)(krow + u*16);
                const int d0 = scb >> 1;   // element d base: 0,32,64,96
                #pragma unroll
                for (int u = 0; u < 4; ++u){
                    short8 vv = *(const short8*)(vrow + u*16);
                    #pragma unroll
                    for (int j = 0; j < 8; ++j){
                        const int d = d0 + u*8 + j;          // d&7 == j
                        *(short*)((char*)Vt + ((d*128 + skey*2) ^ (j << 4))) = vv[j];
                    }
                }
            }
            __syncthreads();

            // ---- QK^T (16 MFMA, 4 independent chains) ----
            float4_ sacc[4] = {};
            __builtin_amdgcn_s_setprio(1);
            #pragma unroll
            for (int kc = 0; kc < 4; ++kc)
                #pragma unroll
                for (int nt = 0; nt < 4; ++nt){
                    short8 kf = *(const short8*)((const char*)Ks +
                        (((nt*16 + l15)*256 + kc*64 + quad*16) ^ ((l15 & 7) << 4)));
                    sacc[nt] = __builtin_amdgcn_mfma_f32_16x16x32_bf16(qf[kc], kf, sacc[nt], 0, 0, 0);
                }
            __builtin_amdgcn_s_setprio(0);

            // ---- scale (exp2 domain) + causal mask, in place ----
            #pragma unroll
            for (int nt = 0; nt < 4; ++nt){
                const int j = kb + nt*16 + l15;
                #pragma unroll
                for (int r = 0; r < 4; ++r){
                    float v = sacc[nt][r] * scale2;
                    sacc[nt][r] = (j > rbase + r) ? -3.0e38f : v;
                }
            }

            // ---- online softmax (reduce across the 16-lane l15 group) ----
            float alpha[4];
            #pragma unroll
            for (int r = 0; r < 4; ++r){
                float v = fmaxf(fmaxf(sacc[0][r], sacc[1][r]), fmaxf(sacc[2][r], sacc[3][r]));
                v = fmaxf(v, m_i[r]);
                #pragma unroll
                for (int off = 1; off < 16; off <<= 1) v = fmaxf(v, __shfl_xor(v, off, 64));
                alpha[r] = exp2f(m_i[r] - v);
                m_i[r] = v;
                float s = 0.0f;
                #pragma unroll
                for (int nt = 0; nt < 4; ++nt){
                    float p = exp2f(sacc[nt][r] - v);
                    sacc[nt][r] = p; s += p;
                }
                #pragma unroll
                for (int off = 1; off < 16; off <<= 1) s += __shfl_xor(s, off, 64);
                l_i[r] = l_i[r]*alpha[r] + s;
            }
            #pragma unroll
            for (int dt = 0; dt < 8; ++dt)
                #pragma unroll
                for (int r = 0; r < 4; ++r) accO[dt][r] *= alpha[r];

            // ---- P: C-layout -> per-wave LDS [16][64] XOR-swz -> A-layout ----
            #pragma unroll
            for (int nt = 0; nt < 4; ++nt)
                #pragma unroll
                for (int r = 0; r < 4; ++r){
                    const int prow = quad*4 + r;
                    *(short*)((char*)Pls + ((w*2048 + prow*128 + (nt*16 + l15)*2)
                                            ^ ((prow & 7) << 4))) = f2bfs(sacc[nt][r]);
                }
            __asm volatile("s_waitcnt lgkmcnt(0)" ::: "memory");
            short8 pf0 = *(const short8*)((const char*)Pls +
                ((w*2048 + l15*128      + quad*16) ^ ((l15 & 7) << 4)));
            short8 pf1 = *(const short8*)((const char*)Pls +
                ((w*2048 + l15*128 + 64 + quad*16) ^ ((l15 & 7) << 4)));

            // ---- PV (16 MFMA) ----
            __builtin_amdgcn_s_setprio(1);
            #pragma unroll
            for (int dt = 0; dt < 8; ++dt){
                const int rb = (dt*16 + l15)*128;
                const int sw = (l15 & 7) << 4;
                short8 vf0 = *(const short8*)((const char*)Vt + ((rb      + quad*16) ^ sw));
                short8 vf1 = *(const short8*)((const char*)Vt + ((rb + 64 + quad*16) ^ sw));
                accO[dt] = __builtin_amdgcn_mfma_f32_16x16x32_bf16(pf0, vf0, accO[dt], 0, 0, 0);
                accO[dt] = __builtin_amdgcn_mfma_f32_16x16x32_bf16(pf1, vf1, accO[dt], 0, 0, 0);
            }
            __builtin_amdgcn_s_setprio(0);
        }

        // ---- normalize + write O into q-slice (race-free: rows owned by block) ----
        float inv[4];
        #pragma unroll
        for (int r = 0; r < 4; ++r) inv[r] = 1.0f / l_i[r];
        #pragma unroll
        for (int dt = 0; dt < 8; ++dt)
            #pragma unroll
            for (int r = 0; r < 4; ++r){
                int s = t*64 + w*16 + quad*4 + r;
                int d = dt*16 + l15;
                Qp[(size_t)s*N3_ + d] = f2bf(accO[dt][r]*inv[r]);
            }
    }
}

// ---------------- launch ----------------
extern "C" void kernel_launch(void* const* d_in, const int* in_sizes, int n_in,
                              void* d_out, int out_size, void* d_ws, size_t ws_size,
                              hipStream_t stream){
    const float* x    = (const float*)d_in[0];
    const float* Wqkv = (const float*)d_in[1];
    const float* bqkv = (const float*)d_in[2];
    const float* Wo   = (const float*)d_in[3];
    const float* bo   = (const float*)d_in[4];
    float* out = (float*)d_out;
    char* ws = (char*)d_ws;

    // qkv is the only mandatory buffer: 8192 x 6144 bf16 = 100,663,296 B (96 MiB)
    bf16* qkv = (bf16*)(ws + 0);

    // Fast path needs additionally: xb 32 MiB + wqkvb 24 MiB + wob 8 MiB -> 160 MiB total
    const size_t OFF_XB = 100663296, OFF_WQ = 134217728, OFF_WO = 159383552;
    const bool big = (ws_size >= (size_t)167772160);

    if (big){
        bf16* xb    = (bf16*)(ws + OFF_XB);
        bf16* wqkvb = (bf16*)(ws + OFF_WQ);
        bf16* wob   = (bf16*)(ws + OFF_WO);
        long n8;
        n8 = (long)M_*D_/8;   cast_f32_bf16<<<(n8+255)/256, 256, 0, stream>>>(x, xb, n8);
        n8 = (long)N3_*D_/8;  cast_f32_bf16<<<(n8+255)/256, 256, 0, stream>>>(Wqkv, wqkvb, n8);
        n8 = (long)D_*D_/8;   cast_f32_bf16<<<(n8+255)/256, 256, 0, stream>>>(Wo, wob, n8);
        gemm_bt<bf16,bf16,bf16><<<dim3(N3_/128, M_/128), 256, 0, stream>>>(
            xb, D_, wqkvb, D_, bqkv, qkv, N3_, D_);
        rope_apply<<<(B_*S_*H_*64)/256, 256, 0, stream>>>(qkv);
        attn<<<dim3(S_/128, B_*H_), 256, 0, stream>>>(qkv);
        gemm_bt<bf16,bf16,float><<<dim3(D_/128, M_/128), 256, 0, stream>>>(
            qkv, N3_, wob, D_, bo, out, D_, D_);
    } else {
        // compact path: fp32 inputs converted during GEMM staging; 96 MiB workspace
        gemm_bt<float,float,bf16><<<dim3(N3_/128, M_/128), 256, 0, stream>>>(
            x, D_, Wqkv, D_, bqkv, qkv, N3_, D_);
        rope_apply<<<(B_*S_*H_*64)/256, 256, 0, stream>>>(qkv);
        attn<<<dim3(S_/128, B_*H_), 256, 0, stream>>>(qkv);
        gemm_bt<bf16,float,float><<<dim3(D_/128, M_/128), 256, 0, stream>>>(
            qkv, N3_, Wo, D_, bo, out, D_, D_);
    }
}